// Round 7
// baseline (227.009 us; speedup 1.0000x reference)
//
#include <hip/hip_runtime.h>

#define NKEYS 64
#define UNROLL 4

typedef int   __attribute__((ext_vector_type(4))) i32x4;
typedef float __attribute__((ext_vector_type(4))) f32x4;

// out[i] = t[x[i]] where t is a 64-entry table derived from (keys, b):
//   t[v] = b[k] if keys[k] == (float)v for integral v in [0,64), else 0.
//
// v7: stream-shape round. Policy matrix is settled (nt loads ~-11us, store
//     policy neutral); kernel sits at ~3.9 TB/s vs 6.3 TB/s copy comparator.
//     Two structural changes targeting read-stream continuity:
//       (a) software pipeline: issue batch k+1's nt loads BEFORE computing/
//           storing batch k, so each wave always has a 4KB read batch in
//           flight (removes the per-iteration read bubble that phase-aligns
//           waves into read-burst/write-burst macro-phases).
//       (b) block-contiguous partitioning: each block owns one contiguous
//           64KB slice walked sequentially (best DRAM page sequentiality),
//           instead of 4 grid-stride passes 32MB apart.
__global__ __launch_bounds__(256) void sel_xform_kernel(
    const i32x4* __restrict__ in,
    const float* __restrict__ b,
    const float* __restrict__ keys,
    f32x4* __restrict__ out,
    int nvec, int slice, int ntail,
    const int* __restrict__ in_tail, float* __restrict__ out_tail)
{
    __shared__ float t[NKEYS];
    const int tid = threadIdx.x;
    if (tid < NKEYS) t[tid] = 0.0f;
    __syncthreads();
    if (tid < NKEYS) {
        const float kv = keys[tid];
        const int iv = (int)kv;
        if ((float)iv == kv && iv >= 0 && iv < NKEYS) {
            t[iv] = b[tid];   // keys are unique -> no write race
        }
    }
    __syncthreads();

    // Scalar tail (n % 4 elements), handled by the first few threads of block 0.
    if (blockIdx.x == 0 && tid < ntail) {
        const int v = in_tail[tid];
        out_tail[tid] = ((unsigned)v < NKEYS) ? t[v] : 0.0f;
    }

    const int B = blockDim.x;  // 256
    const int begin = blockIdx.x * slice;
    if (begin >= nvec) return;
    const int end = (begin + slice < nvec) ? (begin + slice) : nvec;

    // Branch-free table lookup: read t[v&63] (any LDS address is in-bounds),
    // then select 0 for out-of-range values. 64-entry table spans 2 rows of
    // the 32 banks -> worst case 2-way aliasing, which is free (m136).
    auto lut4 = [&](i32x4 v) -> f32x4 {
        const float rx = t[v.x & 63];
        const float ry = t[v.y & 63];
        const float rz = t[v.z & 63];
        const float rw = t[v.w & 63];
        f32x4 o;
        o.x = ((unsigned)v.x < NKEYS) ? rx : 0.0f;
        o.y = ((unsigned)v.y < NKEYS) ? ry : 0.0f;
        o.z = ((unsigned)v.z < NKEYS) ? rz : 0.0f;
        o.w = ((unsigned)v.w < NKEYS) ? rw : 0.0f;
        return o;
    };

    auto loadb = [&](int base, i32x4* dst, bool full) {
#pragma unroll
        for (int j = 0; j < UNROLL; ++j) {
            const int i = base + j * B + tid;
            if (full || i < end) dst[j] = __builtin_nontemporal_load(in + i);
            else                 dst[j] = i32x4{0, 0, 0, 0};
        }
    };
    auto storeb = [&](int base, const i32x4* v, bool full) {
#pragma unroll
        for (int j = 0; j < UNROLL; ++j) {
            const int i = base + j * B + tid;
            if (full || i < end)
                __builtin_nontemporal_store(lut4(v[j]), out + i);
        }
    };

    // Software-pipelined walk of the block's contiguous slice.
    int base = begin;
    i32x4 cur[UNROLL];
    bool cur_full = (base + UNROLL * B) <= end;   // block-uniform
    loadb(base, cur, cur_full);
    while (true) {
        const int nbase = base + UNROLL * B;
        const bool have_next = nbase < end;       // block-uniform
        i32x4 nxt[UNROLL];
        bool nxt_full = false;
        if (have_next) {
            nxt_full = (nbase + UNROLL * B) <= end;
            loadb(nbase, nxt, nxt_full);          // issue BEFORE consuming cur
        }
        storeb(base, cur, cur_full);              // waits only on cur's loads
        if (!have_next) break;
#pragma unroll
        for (int j = 0; j < UNROLL; ++j) cur[j] = nxt[j];
        cur_full = nxt_full;
        base = nbase;
    }
}

extern "C" void kernel_launch(void* const* d_in, const int* in_sizes, int n_in,
                              void* d_out, int out_size, void* d_ws, size_t ws_size,
                              hipStream_t stream) {
    const int*   x    = (const int*)d_in[0];     // inputs, int32, [8,4096,1024]
    const float* b    = (const float*)d_in[1];   // per-key bias, [64]
    const float* keys = (const float*)d_in[2];   // sorted unique keys, [64]
    float* out = (float*)d_out;

    const int n    = in_sizes[0];
    const int nvec = n >> 2;        // int4 / float4 groups
    const int ntail = n & 3;

    const int block = 256;
    const int batch = block * UNROLL;            // 1024 vec4 per block-batch

    // <=2048 blocks, each owning one contiguous slice (multiple of batch).
    int grid = (nvec + batch - 1) / batch;
    if (grid > 2048) grid = 2048;
    if (grid < 1) grid = 1;
    int slice = (nvec + grid - 1) / grid;
    slice = ((slice + batch - 1) / batch) * batch;   // round up to full batches
    grid = (nvec + slice - 1) / slice;               // shrink grid if rounding over-covers

    sel_xform_kernel<<<grid, block, 0, stream>>>(
        (const i32x4*)x, b, keys, (f32x4*)out,
        nvec, slice, ntail, x + (nvec << 2), out + (nvec << 2));
}